// Round 4
// baseline (327.839 us; speedup 1.0000x reference)
//
#include <hip/hip_runtime.h>
#include <hip/hip_bf16.h>
#include <math.h>

#define B_ 32
#define C_ 512
#define N_ 1024
#define D_ 64
#define OPAD 640   // D + C = 576 output channels, padded to 640 for 128-row tiles

typedef __attribute__((ext_vector_type(4))) float f32x4;
typedef __attribute__((ext_vector_type(4))) float float4v;
typedef __attribute__((ext_vector_type(8))) __bf16 bf16x8;

#define MFMA16(a, b, c) __builtin_amdgcn_mfma_f32_16x16x32_bf16((a), (b), (c), 0, 0, 0)

__device__ inline void load_lds16(const void* g, void* l) {
    __builtin_amdgcn_global_load_lds(
        (const __attribute__((address_space(1))) void*)g,
        (__attribute__((address_space(3))) void*)l, 16, 0, 0);
}

// ---------------------------------------------------------------------------
// K1: transpose-cast x [B,C,N] fp32 -> xT [B,N,C] bf16, PLUS (in the first
// 160 blocks) cast w1/w2 into bf16 W [640,512] (rows >=576 zeroed).
// Merging removes one kernel launch.
// ---------------------------------------------------------------------------
__global__ __launch_bounds__(256) void k_transpose_cast(
        const float* __restrict__ x,
        const float* __restrict__ w1, const float* __restrict__ w2,
        __hip_bfloat16* __restrict__ xT, __hip_bfloat16* __restrict__ Wbf) {
    __shared__ float tile[64][68];
    int b = blockIdx.z;
    int n0 = blockIdx.x * 64;
    int c0 = blockIdx.y * 64;
    int t = threadIdx.x;

    // --- W cast side-job: linear block id < 160 covers 640*512 elems ---
    int lid = blockIdx.x + 16 * blockIdx.y + 128 * blockIdx.z;
    if (lid < 160) {
        int base = lid * 2048 + t * 8;       // 8 elems, same row m
        int m = base >> 9, k = base & 511;
        alignas(16) __hip_bfloat16 wtmp[8];
        if (m < D_ + C_) {
            const float* s = (m < D_) ? w1 + (size_t)m * C_ + k
                                      : w2 + (size_t)(m - D_) * C_ + k;
            float4v a = *(const float4v*)s;
            float4v c = *(const float4v*)(s + 4);
            wtmp[0] = __float2bfloat16(a.x); wtmp[1] = __float2bfloat16(a.y);
            wtmp[2] = __float2bfloat16(a.z); wtmp[3] = __float2bfloat16(a.w);
            wtmp[4] = __float2bfloat16(c.x); wtmp[5] = __float2bfloat16(c.y);
            wtmp[6] = __float2bfloat16(c.z); wtmp[7] = __float2bfloat16(c.w);
        } else {
#pragma unroll
            for (int j = 0; j < 8; j++) wtmp[j] = __float2bfloat16(0.0f);
        }
        *(bf16x8*)(Wbf + base) = *(bf16x8*)wtmp;
    }

    const float* xb = x + (size_t)b * (C_ * N_);
#pragma unroll
    for (int i = 0; i < 4; i++) {
        int c = i * 16 + (t >> 4);
        int nc = (t & 15) * 4;
        *(float4v*)&tile[c][nc] =
            *(const float4v*)(xb + (size_t)(c0 + c) * N_ + n0 + nc);
    }
    __syncthreads();
    __hip_bfloat16* xTb = xT + (size_t)b * (N_ * C_);
#pragma unroll
    for (int i = 0; i < 2; i++) {
        int n = i * 32 + (t >> 3);
        int cs = (t & 7) * 8;
        alignas(16) __hip_bfloat16 tmp[8];
#pragma unroll
        for (int j = 0; j < 8; j++)
            tmp[j] = __float2bfloat16(tile[cs + j][n]);
        *(bf16x8*)(xTb + (size_t)(n0 + n) * C_ + c0 + cs) = *(bf16x8*)tmp;
    }
}

// ---------------------------------------------------------------------------
// K2: LDS-staged GEMM  W[640,512] x xT -> qkT [B,N,D] + v [B,C,N].
// BK=64, XOR-swizzled LDS, b-fastest grid (XCD affinity on xT[b]).
// NEW: 2-phase pipeline — double-buffered As/Bs; next tile's
// global_load_lds issued BEFORE this tile's MFMAs; ONE barrier per K-step
// (the __syncthreads vmcnt(0) drain has the whole compute phase to hide
// the staging latency). Epilogue LDS aliased into the dead buffer 0.
// ---------------------------------------------------------------------------
__global__ __launch_bounds__(256) void k_gemm_qkv(
        const __hip_bfloat16* __restrict__ Wbf,
        const __hip_bfloat16* __restrict__ xT,
        const float* __restrict__ b1, const float* __restrict__ b2,
        __hip_bfloat16* __restrict__ qkT, __hip_bfloat16* __restrict__ v) {
    __shared__ __hip_bfloat16 AB[2][2][128 * 64];   // 64 KB
    __hip_bfloat16* epi = &AB[0][0][0];             // [4][16][72] after K-loop
    int b = blockIdx.x;
    int t = threadIdx.x;
    int wave = t >> 6, lane = t & 63, lr = lane & 15, quad = lane >> 4;
    int wm = wave >> 1, wn = wave & 1;
    int m_blk = blockIdx.z * 128;
    int n_blk = blockIdx.y * 128;
    const __hip_bfloat16* xTb = xT + (size_t)b * (N_ * C_);

    // prologue: stage tile 0
#pragma unroll
    for (int i = 0; i < 4; i++) {
        int id = i * 256 + t;
        int r = id >> 3, cx = id & 7, gc = cx ^ (r & 7);
        load_lds16(Wbf + (size_t)(m_blk + r) * C_ + gc * 8, &AB[0][0][id * 8]);
        load_lds16(xTb + (size_t)(n_blk + r) * C_ + gc * 8, &AB[0][1][id * 8]);
    }
    __syncthreads();

    f32x4 acc[4][4] = {};
    for (int tt = 0; tt < 8; tt++) {
        const __hip_bfloat16* As = AB[tt & 1][0];
        const __hip_bfloat16* Bs = AB[tt & 1][1];
        if (tt < 7) {
            int kk = (tt + 1) * 64;
            __hip_bfloat16* An = AB[(tt + 1) & 1][0];
            __hip_bfloat16* Bn = AB[(tt + 1) & 1][1];
#pragma unroll
            for (int i = 0; i < 4; i++) {
                int id = i * 256 + t;
                int r = id >> 3, cx = id & 7, gc = cx ^ (r & 7);
                load_lds16(Wbf + (size_t)(m_blk + r) * C_ + kk + gc * 8, &An[id * 8]);
                load_lds16(xTb + (size_t)(n_blk + r) * C_ + kk + gc * 8, &Bn[id * 8]);
            }
        }
#pragma unroll
        for (int h = 0; h < 2; h++) {
            bf16x8 af[4], bfr[4];
#pragma unroll
            for (int i = 0; i < 4; i++) {
                int ra = wm * 64 + i * 16 + lr;
                int rb = wn * 64 + i * 16 + lr;
                int q = h * 4 + quad;
                af[i]  = *(const bf16x8*)&As[ra * 64 + (q ^ (lr & 7)) * 8];
                bfr[i] = *(const bf16x8*)&Bs[rb * 64 + (q ^ (lr & 7)) * 8];
            }
#pragma unroll
            for (int mt = 0; mt < 4; mt++)
#pragma unroll
                for (int nt = 0; nt < 4; nt++)
                    acc[mt][nt] = MFMA16(af[mt], bfr[nt], acc[mt][nt]);
        }
        __syncthreads();   // drains next-tile stage (vmcnt) + read fences
    }

    // epilogue (epi lives in AB[0], dead after last tile which read AB[1];
    // epi slices are wave-private so no extra barrier needed)
#pragma unroll
    for (int mt = 0; mt < 4; mt++) {
        int m_frag = m_blk + wm * 64 + mt * 16;
        if (m_frag >= D_ + C_) continue;
        int m0 = m_frag + quad * 4;
        if (m_frag < D_) {
#pragma unroll
            for (int nt = 0; nt < 4; nt++) {
                int n = n_blk + wn * 64 + nt * 16 + lr;
                alignas(8) __hip_bfloat16 tmp[4];
#pragma unroll
                for (int r = 0; r < 4; r++)
                    tmp[r] = __float2bfloat16(acc[mt][nt][r] + b1[m0 + r]);
                *reinterpret_cast<short4*>(qkT + ((size_t)b * N_ + n) * D_ + m0) =
                    *reinterpret_cast<short4*>(tmp);
            }
        } else {
#pragma unroll
            for (int nt = 0; nt < 4; nt++) {
#pragma unroll
                for (int r = 0; r < 4; r++) {
                    int c = m0 - D_ + r;
                    epi[(wave * 16 + quad * 4 + r) * 72 + nt * 16 + lr] =
                        __float2bfloat16(acc[mt][nt][r] + b2[c]);
                }
            }
            int cbase = m_frag - D_;
            int row = lane >> 2;
#pragma unroll
            for (int it = 0; it < 2; it++) {
                int col = it * 32 + (lane & 3) * 8;
                bf16x8 frag = *(const bf16x8*)&epi[(wave * 16 + row) * 72 + col];
                *(bf16x8*)(v + (size_t)(b * C_ + cbase + row) * N_
                             + n_blk + wn * 64 + col) = frag;
            }
        }
    }
}

// ---------------------------------------------------------------------------
// K3: fused flash attention + PV GEMM + residual, full c-width per block.
// Grid (b=32, n=8) -> XCD = b%8 (v[b] L2-served).
// NEW: K-fragments live in REGISTERS (double-buffered akA/akB, loaded
// straight from global/L2 for tile t+1 during tile t) — the Ks LDS buffer,
// its staging, and 64 KB/tile of redundant LDS re-reads are gone; the
// S-phase MFMAs start with zero ds_reads after the barrier.
// LDS: Vs0 64K + Vs1 64K + Ps 16K = 144 KB (+Rs). 1 block/CU, grid=256.
// ---------------------------------------------------------------------------
__global__ __launch_bounds__(512, 2) void k_fused_attn(
        const __hip_bfloat16* __restrict__ qkT,
        const __hip_bfloat16* __restrict__ v,
        const float* __restrict__ x, float* __restrict__ out) {
    __shared__ char smem[147456];
    __hip_bfloat16* Vs0 = (__hip_bfloat16*)smem;             // [512][64]  64 KB
    __hip_bfloat16* Vs1 = (__hip_bfloat16*)(smem + 65536);   // [512][64]  64 KB
    __hip_bfloat16* Ps  = (__hip_bfloat16*)(smem + 131072);  // [128][64]  16 KB
    float* Obuf = (float*)smem;                              // [64][260] fp32 epi
    __shared__ float Rs[128];

    int b = blockIdx.x;
    int t = threadIdx.x;
    int wave = t >> 6, lane = t & 63, lr = lane & 15, quad = lane >> 4;
    int wm = wave >> 2, wn = wave & 3;
    int n_blk = blockIdx.y * 128;
    const __hip_bfloat16* qb = qkT + (size_t)b * (N_ * D_);
    const __hip_bfloat16* vb = v + (size_t)b * (C_ * N_);

    // prologue: stage Vs0 (tile 0) + load tile-0 K-fragments to registers
#pragma unroll
    for (int i = 0; i < 8; i++) {
        int id = i * 512 + t;
        int r = id >> 3, cxx = id & 7, gc = cxx ^ (r & 7);
        load_lds16(vb + (size_t)r * N_ + gc * 8, &Vs0[id * 8]);
    }
    bf16x8 akA[4][2], akB[4][2];
#pragma unroll
    for (int mi = 0; mi < 4; mi++) {
        akA[mi][0] = *(const bf16x8*)(qb + (size_t)(mi * 16 + lr) * D_ + quad * 8);
        akA[mi][1] = *(const bf16x8*)(qb + (size_t)(mi * 16 + lr) * D_ + 32 + quad * 8);
    }

    // Q fragment (B operand of S^T) + softmax shift = ||q_n||^2 (diagonal):
    // rowsum >= 1 (diag term e^0), off-diag exp <= ~e^30 -> fp32/bf16 safe.
    union bfu { bf16x8 v; __hip_bfloat16 h[8]; };
    bf16x8 bq[2];
    float shift;
    {
        int nq = n_blk + wave * 16 + lr;
        bq[0] = *(const bf16x8*)(qb + (size_t)nq * D_ + quad * 8);
        bq[1] = *(const bf16x8*)(qb + (size_t)nq * D_ + 32 + quad * 8);
        float sq = 0.f;
#pragma unroll
        for (int dh = 0; dh < 2; dh++) {
            bfu u; u.v = bq[dh];
#pragma unroll
            for (int j = 0; j < 8; j++) {
                float qv = __bfloat162float(u.h[j]);
                sq += qv * qv;
            }
        }
        sq += __shfl_xor(sq, 16);
        sq += __shfl_xor(sq, 32);
        shift = sq;
    }

    f32x4 acc[4][8] = {};
    float rsum = 0.f;

    __syncthreads();   // tile 0 staged (vmcnt(0) also covers akA/bq loads)

#define ATTN_TILE(TT, VCUR, VNXT, AKC, AKN)                                    \
    {                                                                          \
        const int kk = (TT) * 64;                                              \
        if ((TT) < 15) {                                                       \
            _Pragma("unroll")                                                  \
            for (int i = 0; i < 8; i++) {                                      \
                int id = i * 512 + t;                                          \
                int r = id >> 3, cxx = id & 7, gc = cxx ^ (r & 7);             \
                load_lds16(vb + (size_t)r * N_ + kk + 64 + gc * 8,             \
                           &VNXT[id * 8]);                                     \
            }                                                                  \
            _Pragma("unroll")                                                  \
            for (int mi = 0; mi < 4; mi++) {                                   \
                AKN[mi][0] = *(const bf16x8*)(qb                               \
                    + (size_t)(kk + 64 + mi * 16 + lr) * D_ + quad * 8);       \
                AKN[mi][1] = *(const bf16x8*)(qb                               \
                    + (size_t)(kk + 64 + mi * 16 + lr) * D_ + 32 + quad * 8);  \
            }                                                                  \
        }                                                                      \
        _Pragma("unroll")                                                      \
        for (int mi = 0; mi < 4; mi++) {                                       \
            f32x4 s = {};                                                      \
            s = MFMA16(AKC[mi][0], bq[0], s);                                  \
            s = MFMA16(AKC[mi][1], bq[1], s);                                  \
            alignas(8) __hip_bfloat16 tmp[4];                                  \
            _Pragma("unroll")                                                  \
            for (int r = 0; r < 4; r++) {                                      \
                float e = __expf(s[r] - shift);                                \
                rsum += e;                                                     \
                tmp[r] = __float2bfloat16(e);                                  \
            }                                                                  \
            int n = wave * 16 + lr;                                            \
            int cx2 = mi * 2 + (quad >> 1);                                    \
            int slot = cx2 ^ (lr & 7);                                         \
            *(short4*)&Ps[n * 64 + slot * 8 + (quad & 1) * 4] = *(short4*)tmp; \
        }                                                                      \
        asm volatile("s_waitcnt lgkmcnt(0)" ::: "memory");                     \
        __builtin_amdgcn_s_barrier();                                          \
        __builtin_amdgcn_sched_barrier(0);                                     \
        _Pragma("unroll")                                                      \
        for (int h = 0; h < 2; h++) {                                          \
            bf16x8 af[4];                                                      \
            _Pragma("unroll")                                                  \
            for (int i = 0; i < 4; i++) {                                      \
                int ra = wm * 64 + i * 16 + lr;                                \
                af[i] = *(const bf16x8*)&Ps[ra * 64                            \
                        + ((h * 4 + quad) ^ (lr & 7)) * 8];                    \
            }                                                                  \
            _Pragma("unroll")                                                  \
            for (int g = 0; g < 2; g++) {                                      \
                bf16x8 bfr[4];                                                 \
                _Pragma("unroll")                                              \
                for (int j = 0; j < 4; j++) {                                  \
                    int rb = wn * 128 + (g * 4 + j) * 16 + lr;                 \
                    bfr[j] = *(const bf16x8*)&VCUR[rb * 64                     \
                             + ((h * 4 + quad) ^ (lr & 7)) * 8];               \
                }                                                              \
                _Pragma("unroll")                                              \
                for (int mt = 0; mt < 4; mt++)                                 \
                    _Pragma("unroll")                                          \
                    for (int j = 0; j < 4; j++)                                \
                        acc[mt][g * 4 + j] =                                   \
                            MFMA16(af[mt], bfr[j], acc[mt][g * 4 + j]);        \
            }                                                                  \
        }                                                                      \
        __syncthreads();                                                       \
    }

    for (int tt = 0; tt < 16; tt += 2) {
        ATTN_TILE(tt,     Vs0, Vs1, akA, akB);
        ATTN_TILE(tt + 1, Vs1, Vs0, akB, akA);
    }
#undef ATTN_TILE

    // rowinv: reduce partial sums across the 4 quads
    rsum += __shfl_xor(rsum, 16);
    rsum += __shfl_xor(rsum, 32);
    if (quad == 0) Rs[wave * 16 + lr] = 1.0f / rsum;

    // epilogue: 4 phases (h = n-half, g = c-half) through LDS Obuf[64][260]
    const float* xb = x + (size_t)b * (N_ * C_);
    float* ob = out + (size_t)b * (N_ * C_);
#pragma unroll
    for (int h = 0; h < 2; h++) {
#pragma unroll
        for (int g = 0; g < 2; g++) {
            __syncthreads();   // Obuf free; publishes Rs on first pass
            if (wm == h && (wn >> 1) == g) {
#pragma unroll
                for (int mt = 0; mt < 4; mt++)
#pragma unroll
                    for (int nt = 0; nt < 8; nt++)
#pragma unroll
                        for (int r = 0; r < 4; r++)
                            Obuf[(mt * 16 + quad * 4 + r) * 260
                                 + (wn & 1) * 128 + nt * 16 + lr] =
                                acc[mt][nt][r];
            }
            __syncthreads();
#pragma unroll
            for (int i = 0; i < 8; i++) {
                int id = i * 512 + t;
                int rl = id >> 6;              // 0..63
                int c4 = (id & 63) * 4;        // float4 col 0..252
                int n = n_blk + h * 64 + rl;
                float ri = Rs[h * 64 + rl];
                float4v o = *(const float4v*)&Obuf[rl * 260 + c4];
                size_t gidx = (size_t)n * C_ + g * 256 + c4;
                float4v xv = *(const float4v*)(xb + gidx);
                float4v res;
                res.x = xv.x + ri * o.x;
                res.y = xv.y + ri * o.y;
                res.z = xv.z + ri * o.z;
                res.w = xv.w + ri * o.w;
                *(float4v*)(ob + gidx) = res;
            }
        }
    }
}

// ---------------------------------------------------------------------------
extern "C" void kernel_launch(void* const* d_in, const int* in_sizes, int n_in,
                              void* d_out, int out_size, void* d_ws, size_t ws_size,
                              hipStream_t stream) {
    const float* x  = (const float*)d_in[0];
    const float* w1 = (const float*)d_in[1];
    const float* b1 = (const float*)d_in[2];
    const float* w2 = (const float*)d_in[3];
    const float* b2 = (const float*)d_in[4];
    float* out = (float*)d_out;

    char* ws = (char*)d_ws;
    size_t off = 0;
    __hip_bfloat16* Wbf = (__hip_bfloat16*)(ws + off); off += (size_t)OPAD * C_ * 2;
    __hip_bfloat16* xT  = (__hip_bfloat16*)(ws + off); off += (size_t)B_ * N_ * C_ * 2;
    __hip_bfloat16* qkT = (__hip_bfloat16*)(ws + off); off += (size_t)B_ * N_ * D_ * 2;
    __hip_bfloat16* v   = (__hip_bfloat16*)(ws + off); off += (size_t)B_ * C_ * N_ * 2;

    hipLaunchKernelGGL(k_transpose_cast, dim3(N_ / 64, C_ / 64, B_), dim3(256), 0, stream,
                       x, w1, w2, xT, Wbf);
    hipLaunchKernelGGL(k_gemm_qkv, dim3(B_, N_ / 128, OPAD / 128), dim3(256), 0, stream,
                       Wbf, xT, b1, b2, qkT, v);
    hipLaunchKernelGGL(k_fused_attn, dim3(B_, N_ / 128), dim3(512), 0, stream,
                       qkT, v, x, out);
}

// Round 5
// 241.335 us; speedup vs baseline: 1.3584x; 1.3584x over previous
//
#include <hip/hip_runtime.h>
#include <hip/hip_bf16.h>
#include <math.h>

#define B_ 32
#define C_ 512
#define N_ 1024
#define D_ 64
#define OPAD 640   // D + C = 576 output channels, padded to 640 for 128-row tiles

typedef __attribute__((ext_vector_type(4))) float f32x4;
typedef __attribute__((ext_vector_type(4))) float float4v;
typedef __attribute__((ext_vector_type(8))) __bf16 bf16x8;

#define MFMA16(a, b, c) __builtin_amdgcn_mfma_f32_16x16x32_bf16((a), (b), (c), 0, 0, 0)

__device__ inline void load_lds16(const void* g, void* l) {
    __builtin_amdgcn_global_load_lds(
        (const __attribute__((address_space(1))) void*)g,
        (__attribute__((address_space(3))) void*)l, 16, 0, 0);
}

// ---------------------------------------------------------------------------
// K1: transpose-cast x [B,C,N] fp32 -> xT [B,N,C] bf16, PLUS (in the first
// 160 blocks) cast w1/w2 into bf16 W [640,512] (rows >=576 zeroed).
// ---------------------------------------------------------------------------
__global__ __launch_bounds__(256) void k_transpose_cast(
        const float* __restrict__ x,
        const float* __restrict__ w1, const float* __restrict__ w2,
        __hip_bfloat16* __restrict__ xT, __hip_bfloat16* __restrict__ Wbf) {
    __shared__ float tile[64][68];
    int b = blockIdx.z;
    int n0 = blockIdx.x * 64;
    int c0 = blockIdx.y * 64;
    int t = threadIdx.x;

    // --- W cast side-job: linear block id < 160 covers 640*512 elems ---
    int lid = blockIdx.x + 16 * blockIdx.y + 128 * blockIdx.z;
    if (lid < 160) {
        int base = lid * 2048 + t * 8;       // 8 elems, same row m
        int m = base >> 9, k = base & 511;
        alignas(16) __hip_bfloat16 wtmp[8];
        if (m < D_ + C_) {
            const float* s = (m < D_) ? w1 + (size_t)m * C_ + k
                                      : w2 + (size_t)(m - D_) * C_ + k;
            float4v a = *(const float4v*)s;
            float4v c = *(const float4v*)(s + 4);
            wtmp[0] = __float2bfloat16(a.x); wtmp[1] = __float2bfloat16(a.y);
            wtmp[2] = __float2bfloat16(a.z); wtmp[3] = __float2bfloat16(a.w);
            wtmp[4] = __float2bfloat16(c.x); wtmp[5] = __float2bfloat16(c.y);
            wtmp[6] = __float2bfloat16(c.z); wtmp[7] = __float2bfloat16(c.w);
        } else {
#pragma unroll
            for (int j = 0; j < 8; j++) wtmp[j] = __float2bfloat16(0.0f);
        }
        *(bf16x8*)(Wbf + base) = *(bf16x8*)wtmp;
    }

    const float* xb = x + (size_t)b * (C_ * N_);
#pragma unroll
    for (int i = 0; i < 4; i++) {
        int c = i * 16 + (t >> 4);
        int nc = (t & 15) * 4;
        *(float4v*)&tile[c][nc] =
            *(const float4v*)(xb + (size_t)(c0 + c) * N_ + n0 + nc);
    }
    __syncthreads();
    __hip_bfloat16* xTb = xT + (size_t)b * (N_ * C_);
#pragma unroll
    for (int i = 0; i < 2; i++) {
        int n = i * 32 + (t >> 3);
        int cs = (t & 7) * 8;
        alignas(16) __hip_bfloat16 tmp[8];
#pragma unroll
        for (int j = 0; j < 8; j++)
            tmp[j] = __float2bfloat16(tile[cs + j][n]);
        *(bf16x8*)(xTb + (size_t)(n0 + n) * C_ + c0 + cs) = *(bf16x8*)tmp;
    }
}

// ---------------------------------------------------------------------------
// K2: LDS-staged GEMM  W[640,512] x xT -> qkT [B,N,D] + v [B,C,N].
// BK=64, XOR-swizzled LDS, b-fastest grid (XCD affinity on xT[b]).
// 2-phase pipeline: double-buffered As/Bs; next tile's global_load_lds
// issued BEFORE this tile's MFMAs; ONE barrier per K-step.
// ---------------------------------------------------------------------------
__global__ __launch_bounds__(256) void k_gemm_qkv(
        const __hip_bfloat16* __restrict__ Wbf,
        const __hip_bfloat16* __restrict__ xT,
        const float* __restrict__ b1, const float* __restrict__ b2,
        __hip_bfloat16* __restrict__ qkT, __hip_bfloat16* __restrict__ v) {
    __shared__ __hip_bfloat16 AB[2][2][128 * 64];   // 64 KB
    __hip_bfloat16* epi = &AB[0][0][0];             // [4][16][72] after K-loop
    int b = blockIdx.x;
    int t = threadIdx.x;
    int wave = t >> 6, lane = t & 63, lr = lane & 15, quad = lane >> 4;
    int wm = wave >> 1, wn = wave & 1;
    int m_blk = blockIdx.z * 128;
    int n_blk = blockIdx.y * 128;
    const __hip_bfloat16* xTb = xT + (size_t)b * (N_ * C_);

    // prologue: stage tile 0
#pragma unroll
    for (int i = 0; i < 4; i++) {
        int id = i * 256 + t;
        int r = id >> 3, cx = id & 7, gc = cx ^ (r & 7);
        load_lds16(Wbf + (size_t)(m_blk + r) * C_ + gc * 8, &AB[0][0][id * 8]);
        load_lds16(xTb + (size_t)(n_blk + r) * C_ + gc * 8, &AB[0][1][id * 8]);
    }
    __syncthreads();

    f32x4 acc[4][4] = {};
    for (int tt = 0; tt < 8; tt++) {
        const __hip_bfloat16* As = AB[tt & 1][0];
        const __hip_bfloat16* Bs = AB[tt & 1][1];
        if (tt < 7) {
            int kk = (tt + 1) * 64;
            __hip_bfloat16* An = AB[(tt + 1) & 1][0];
            __hip_bfloat16* Bn = AB[(tt + 1) & 1][1];
#pragma unroll
            for (int i = 0; i < 4; i++) {
                int id = i * 256 + t;
                int r = id >> 3, cx = id & 7, gc = cx ^ (r & 7);
                load_lds16(Wbf + (size_t)(m_blk + r) * C_ + kk + gc * 8, &An[id * 8]);
                load_lds16(xTb + (size_t)(n_blk + r) * C_ + kk + gc * 8, &Bn[id * 8]);
            }
        }
#pragma unroll
        for (int h = 0; h < 2; h++) {
            bf16x8 af[4], bfr[4];
#pragma unroll
            for (int i = 0; i < 4; i++) {
                int ra = wm * 64 + i * 16 + lr;
                int rb = wn * 64 + i * 16 + lr;
                int q = h * 4 + quad;
                af[i]  = *(const bf16x8*)&As[ra * 64 + (q ^ (lr & 7)) * 8];
                bfr[i] = *(const bf16x8*)&Bs[rb * 64 + (q ^ (lr & 7)) * 8];
            }
#pragma unroll
            for (int mt = 0; mt < 4; mt++)
#pragma unroll
                for (int nt = 0; nt < 4; nt++)
                    acc[mt][nt] = MFMA16(af[mt], bfr[nt], acc[mt][nt]);
        }
        __syncthreads();   // drains next-tile stage (vmcnt) + read fences
    }

    // epilogue (epi lives in AB[0], dead after last tile which read AB[1];
    // epi slices are wave-private so no extra barrier needed)
#pragma unroll
    for (int mt = 0; mt < 4; mt++) {
        int m_frag = m_blk + wm * 64 + mt * 16;
        if (m_frag >= D_ + C_) continue;
        int m0 = m_frag + quad * 4;
        if (m_frag < D_) {
#pragma unroll
            for (int nt = 0; nt < 4; nt++) {
                int n = n_blk + wn * 64 + nt * 16 + lr;
                alignas(8) __hip_bfloat16 tmp[4];
#pragma unroll
                for (int r = 0; r < 4; r++)
                    tmp[r] = __float2bfloat16(acc[mt][nt][r] + b1[m0 + r]);
                *reinterpret_cast<short4*>(qkT + ((size_t)b * N_ + n) * D_ + m0) =
                    *reinterpret_cast<short4*>(tmp);
            }
        } else {
#pragma unroll
            for (int nt = 0; nt < 4; nt++) {
#pragma unroll
                for (int r = 0; r < 4; r++) {
                    int c = m0 - D_ + r;
                    epi[(wave * 16 + quad * 4 + r) * 72 + nt * 16 + lr] =
                        __float2bfloat16(acc[mt][nt][r] + b2[c]);
                }
            }
            int cbase = m_frag - D_;
            int row = lane >> 2;
#pragma unroll
            for (int it = 0; it < 2; it++) {
                int col = it * 32 + (lane & 3) * 8;
                bf16x8 frag = *(const bf16x8*)&epi[(wave * 16 + row) * 72 + col];
                *(bf16x8*)(v + (size_t)(b * C_ + cbase + row) * N_
                             + n_blk + wn * 64 + col) = frag;
            }
        }
    }
}

// ---------------------------------------------------------------------------
// K3: fused flash attention + PV GEMM + residual, full c-width per block.
// Grid (b=32, n=8) -> XCD = b%8 (v[b] and qkT[b] L2-resident).
// This round: NO V LDS staging — PV's B-fragments are loaded directly from
// global (L2-hot, contiguous in m). Ks and Ps are double-buffered, giving
// ONE __syncthreads per tile: wave A's S(t+1) overlaps wave B's PV(t).
// LDS: Ks dbuf 16K + Ps dbuf 32K = 48 KB (+epilogue alias 66.5 KB).
// Register budget: 8 waves/CU -> 256/wave; acc[4][8]=128 AGPR, non-acc
// VGPRs kept at round-3 level (~124) — no new persistent register state.
// ---------------------------------------------------------------------------
__global__ __launch_bounds__(512, 2) void k_fused_attn(
        const __hip_bfloat16* __restrict__ qkT,
        const __hip_bfloat16* __restrict__ v,
        const float* __restrict__ x, float* __restrict__ out) {
    __shared__ char smem[67072];
    __hip_bfloat16* Ks0 = (__hip_bfloat16*)smem;             // [64][64]   8 KB
    __hip_bfloat16* Ks1 = (__hip_bfloat16*)(smem + 8192);    // [64][64]   8 KB
    __hip_bfloat16* Ps0 = (__hip_bfloat16*)(smem + 16384);   // [128][64] 16 KB
    __hip_bfloat16* Ps1 = (__hip_bfloat16*)(smem + 49152);   // [128][64] 16 KB
    float* Obuf = (float*)smem;                              // [64][260] fp32 epi
    __shared__ float Rs[128];

    int b = blockIdx.x;
    int t = threadIdx.x;
    int wave = t >> 6, lane = t & 63, lr = lane & 15, quad = lane >> 4;
    int wm = wave >> 2, wn = wave & 3;
    int n_blk = blockIdx.y * 128;
    const __hip_bfloat16* qb = qkT + (size_t)b * (N_ * D_);
    const __hip_bfloat16* vb = v + (size_t)b * (C_ * N_);

    // prologue: stage Ks(0); Q-fragment + shift compute overlaps the latency
    {
        int r = t >> 3, cxx = t & 7, gc = cxx ^ (r & 7);
        load_lds16(qb + (size_t)r * D_ + gc * 8, &Ks0[t * 8]);
    }

    // Q fragment (B operand of S^T) + softmax shift = ||q_n||^2 (diagonal):
    // rowsum >= 1 (diag term e^0), off-diag exp <= ~e^30 -> fp32/bf16 safe.
    union bfu { bf16x8 v; __hip_bfloat16 h[8]; };
    bf16x8 bq[2];
    float shift;
    {
        int nq = n_blk + wave * 16 + lr;
        bq[0] = *(const bf16x8*)(qb + (size_t)nq * D_ + quad * 8);
        bq[1] = *(const bf16x8*)(qb + (size_t)nq * D_ + 32 + quad * 8);
        float sq = 0.f;
#pragma unroll
        for (int dh = 0; dh < 2; dh++) {
            bfu u; u.v = bq[dh];
#pragma unroll
            for (int j = 0; j < 8; j++) {
                float qv = __bfloat162float(u.h[j]);
                sq += qv * qv;
            }
        }
        sq += __shfl_xor(sq, 16);
        sq += __shfl_xor(sq, 32);
        shift = sq;
    }

    f32x4 acc[4][8] = {};
    float rsum = 0.f;

    __syncthreads();   // Ks(0) staged

    for (int tt = 0; tt < 16; ++tt) {
        const int kk = tt * 64;
        __hip_bfloat16* Kst = (tt & 1) ? Ks1 : Ks0;
        __hip_bfloat16* Ksn = (tt & 1) ? Ks0 : Ks1;
        __hip_bfloat16* Pst = (tt & 1) ? Ps1 : Ps0;

        // stage Ks(t+1) (8 KB; drained by this tile's mid __syncthreads)
        if (tt < 15) {
            int r = t >> 3, cxx = t & 7, gc = cxx ^ (r & 7);
            load_lds16(qb + (size_t)(kk + 64 + r) * D_ + gc * 8, &Ksn[t * 8]);
        }

        // S-phase: this wave's 16 n-cols x 64 m; exp + rowsum + Ps(t) write
#pragma unroll
        for (int mi = 0; mi < 4; mi++) {
            int m = mi * 16 + lr;
            bf16x8 ak0 = *(const bf16x8*)&Kst[m * 64 + ((quad) ^ (lr & 7)) * 8];
            bf16x8 ak1 = *(const bf16x8*)&Kst[m * 64 + ((4 + quad) ^ (lr & 7)) * 8];
            f32x4 s = {};
            s = MFMA16(ak0, bq[0], s);
            s = MFMA16(ak1, bq[1], s);
            alignas(8) __hip_bfloat16 tmp[4];
#pragma unroll
            for (int r = 0; r < 4; r++) {
                float e = __expf(s[r] - shift);
                rsum += e;
                tmp[r] = __float2bfloat16(e);
            }
            // lane holds m = mi*16 + quad*4 + {0..3} (contiguous), col n
            int n = wave * 16 + lr;
            int cx2 = mi * 2 + (quad >> 1);
            int slot = cx2 ^ (lr & 7);
            *(short4*)&Pst[n * 64 + slot * 8 + (quad & 1) * 4] = *(short4*)tmp;
        }

        // single barrier per tile: Ps(t) published, Ks(t+1) stage drained.
        // Ps double-buffer lets waves skew: S(t+1) overlaps others' PV(t).
        __syncthreads();

        // PV: acc[n 64][c 128] += Ps(t) (A, LDS) x V (B, direct from L2)
#pragma unroll
        for (int h = 0; h < 2; h++) {
            bf16x8 af[4];
#pragma unroll
            for (int i = 0; i < 4; i++) {
                int ra = wm * 64 + i * 16 + lr;
                af[i] = *(const bf16x8*)&Pst[ra * 64 + ((h * 4 + quad) ^ (lr & 7)) * 8];
            }
#pragma unroll
            for (int g = 0; g < 2; g++) {
                bf16x8 bfr[4];
#pragma unroll
                for (int j = 0; j < 4; j++) {
                    int rb = wn * 128 + (g * 4 + j) * 16 + lr;
                    bfr[j] = *(const bf16x8*)(vb + (size_t)rb * N_ + kk
                                              + (h * 4 + quad) * 8);
                }
#pragma unroll
                for (int mt = 0; mt < 4; mt++)
#pragma unroll
                    for (int j = 0; j < 4; j++)
                        acc[mt][g * 4 + j] = MFMA16(af[mt], bfr[j], acc[mt][g * 4 + j]);
            }
        }
        // no trailing barrier: next tile writes Ps(t^1)/Ks(t^1) only
    }

    // rowinv: reduce partial sums across the 4 quads
    rsum += __shfl_xor(rsum, 16);
    rsum += __shfl_xor(rsum, 32);
    if (quad == 0) Rs[wave * 16 + lr] = 1.0f / rsum;

    // epilogue: 4 phases (h = n-half, g = c-half) through LDS Obuf[64][260]
    const float* xb = x + (size_t)b * (N_ * C_);
    float* ob = out + (size_t)b * (N_ * C_);
#pragma unroll
    for (int h = 0; h < 2; h++) {
#pragma unroll
        for (int g = 0; g < 2; g++) {
            __syncthreads();   // all PV(15) reads done; Obuf free; Rs visible
            if (wm == h && (wn >> 1) == g) {
#pragma unroll
                for (int mt = 0; mt < 4; mt++)
#pragma unroll
                    for (int nt = 0; nt < 8; nt++)
#pragma unroll
                        for (int r = 0; r < 4; r++)
                            Obuf[(mt * 16 + quad * 4 + r) * 260
                                 + (wn & 1) * 128 + nt * 16 + lr] =
                                acc[mt][nt][r];
            }
            __syncthreads();
#pragma unroll
            for (int i = 0; i < 8; i++) {
                int id = i * 512 + t;
                int rl = id >> 6;              // 0..63
                int c4 = (id & 63) * 4;        // float4 col 0..252
                int n = n_blk + h * 64 + rl;
                float ri = Rs[h * 64 + rl];
                float4v o = *(const float4v*)&Obuf[rl * 260 + c4];
                size_t gidx = (size_t)n * C_ + g * 256 + c4;
                float4v xv = *(const float4v*)(xb + gidx);
                float4v res;
                res.x = xv.x + ri * o.x;
                res.y = xv.y + ri * o.y;
                res.z = xv.z + ri * o.z;
                res.w = xv.w + ri * o.w;
                *(float4v*)(ob + gidx) = res;
            }
        }
    }
}

// ---------------------------------------------------------------------------
extern "C" void kernel_launch(void* const* d_in, const int* in_sizes, int n_in,
                              void* d_out, int out_size, void* d_ws, size_t ws_size,
                              hipStream_t stream) {
    const float* x  = (const float*)d_in[0];
    const float* w1 = (const float*)d_in[1];
    const float* b1 = (const float*)d_in[2];
    const float* w2 = (const float*)d_in[3];
    const float* b2 = (const float*)d_in[4];
    float* out = (float*)d_out;

    char* ws = (char*)d_ws;
    size_t off = 0;
    __hip_bfloat16* Wbf = (__hip_bfloat16*)(ws + off); off += (size_t)OPAD * C_ * 2;
    __hip_bfloat16* xT  = (__hip_bfloat16*)(ws + off); off += (size_t)B_ * N_ * C_ * 2;
    __hip_bfloat16* qkT = (__hip_bfloat16*)(ws + off); off += (size_t)B_ * N_ * D_ * 2;
    __hip_bfloat16* v   = (__hip_bfloat16*)(ws + off); off += (size_t)B_ * C_ * N_ * 2;

    hipLaunchKernelGGL(k_transpose_cast, dim3(N_ / 64, C_ / 64, B_), dim3(256), 0, stream,
                       x, w1, w2, xT, Wbf);
    hipLaunchKernelGGL(k_gemm_qkv, dim3(B_, N_ / 128, OPAD / 128), dim3(256), 0, stream,
                       Wbf, xT, b1, b2, qkT, v);
    hipLaunchKernelGGL(k_fused_attn, dim3(B_, N_ / 128), dim3(512), 0, stream,
                       qkT, v, x, out);
}

// Round 6
// 199.776 us; speedup vs baseline: 1.6410x; 1.2080x over previous
//
#include <hip/hip_runtime.h>
#include <hip/hip_bf16.h>
#include <math.h>

#define B_ 32
#define C_ 512
#define N_ 1024
#define D_ 64
#define OPAD 640   // D + C = 576 output channels, padded to 640 for 128-row tiles

typedef __attribute__((ext_vector_type(4))) float f32x4;
typedef __attribute__((ext_vector_type(4))) float float4v;
typedef __attribute__((ext_vector_type(8))) __bf16 bf16x8;

#define MFMA16(a, b, c) __builtin_amdgcn_mfma_f32_16x16x32_bf16((a), (b), (c), 0, 0, 0)

__device__ inline void load_lds16(const void* g, void* l) {
    __builtin_amdgcn_global_load_lds(
        (const __attribute__((address_space(1))) void*)g,
        (__attribute__((address_space(3))) void*)l, 16, 0, 0);
}

// ---------------------------------------------------------------------------
// K1: transpose-cast x [B,C,N] fp32 -> xT [B,N,C] bf16, PLUS (in the first
// 160 blocks) cast w1/w2 into bf16 W [640,512] (rows >=576 zeroed).
// ---------------------------------------------------------------------------
__global__ __launch_bounds__(256) void k_transpose_cast(
        const float* __restrict__ x,
        const float* __restrict__ w1, const float* __restrict__ w2,
        __hip_bfloat16* __restrict__ xT, __hip_bfloat16* __restrict__ Wbf) {
    __shared__ float tile[64][68];
    int b = blockIdx.z;
    int n0 = blockIdx.x * 64;
    int c0 = blockIdx.y * 64;
    int t = threadIdx.x;

    // --- W cast side-job: linear block id < 160 covers 640*512 elems ---
    int lid = blockIdx.x + 16 * blockIdx.y + 128 * blockIdx.z;
    if (lid < 160) {
        int base = lid * 2048 + t * 8;       // 8 elems, same row m
        int m = base >> 9, k = base & 511;
        alignas(16) __hip_bfloat16 wtmp[8];
        if (m < D_ + C_) {
            const float* s = (m < D_) ? w1 + (size_t)m * C_ + k
                                      : w2 + (size_t)(m - D_) * C_ + k;
            float4v a = *(const float4v*)s;
            float4v c = *(const float4v*)(s + 4);
            wtmp[0] = __float2bfloat16(a.x); wtmp[1] = __float2bfloat16(a.y);
            wtmp[2] = __float2bfloat16(a.z); wtmp[3] = __float2bfloat16(a.w);
            wtmp[4] = __float2bfloat16(c.x); wtmp[5] = __float2bfloat16(c.y);
            wtmp[6] = __float2bfloat16(c.z); wtmp[7] = __float2bfloat16(c.w);
        } else {
#pragma unroll
            for (int j = 0; j < 8; j++) wtmp[j] = __float2bfloat16(0.0f);
        }
        *(bf16x8*)(Wbf + base) = *(bf16x8*)wtmp;
    }

    const float* xb = x + (size_t)b * (C_ * N_);
#pragma unroll
    for (int i = 0; i < 4; i++) {
        int c = i * 16 + (t >> 4);
        int nc = (t & 15) * 4;
        *(float4v*)&tile[c][nc] =
            *(const float4v*)(xb + (size_t)(c0 + c) * N_ + n0 + nc);
    }
    __syncthreads();
    __hip_bfloat16* xTb = xT + (size_t)b * (N_ * C_);
#pragma unroll
    for (int i = 0; i < 2; i++) {
        int n = i * 32 + (t >> 3);
        int cs = (t & 7) * 8;
        alignas(16) __hip_bfloat16 tmp[8];
#pragma unroll
        for (int j = 0; j < 8; j++)
            tmp[j] = __float2bfloat16(tile[cs + j][n]);
        *(bf16x8*)(xTb + (size_t)(n0 + n) * C_ + c0 + cs) = *(bf16x8*)tmp;
    }
}

// ---------------------------------------------------------------------------
// K2: LDS-staged GEMM  W[640,512] x xT -> qkT [B,N,D] + v [B,C,N].
// BK=64, XOR-swizzled LDS, b-fastest grid (XCD affinity on xT[b]).
// 2-phase pipeline: double-buffered As/Bs; next tile's global_load_lds
// issued BEFORE this tile's MFMAs; ONE barrier per K-step.
// ---------------------------------------------------------------------------
__global__ __launch_bounds__(256) void k_gemm_qkv(
        const __hip_bfloat16* __restrict__ Wbf,
        const __hip_bfloat16* __restrict__ xT,
        const float* __restrict__ b1, const float* __restrict__ b2,
        __hip_bfloat16* __restrict__ qkT, __hip_bfloat16* __restrict__ v) {
    __shared__ __hip_bfloat16 AB[2][2][128 * 64];   // 64 KB
    __hip_bfloat16* epi = &AB[0][0][0];             // [4][16][72] after K-loop
    int b = blockIdx.x;
    int t = threadIdx.x;
    int wave = t >> 6, lane = t & 63, lr = lane & 15, quad = lane >> 4;
    int wm = wave >> 1, wn = wave & 1;
    int m_blk = blockIdx.z * 128;
    int n_blk = blockIdx.y * 128;
    const __hip_bfloat16* xTb = xT + (size_t)b * (N_ * C_);

    // prologue: stage tile 0
#pragma unroll
    for (int i = 0; i < 4; i++) {
        int id = i * 256 + t;
        int r = id >> 3, cx = id & 7, gc = cx ^ (r & 7);
        load_lds16(Wbf + (size_t)(m_blk + r) * C_ + gc * 8, &AB[0][0][id * 8]);
        load_lds16(xTb + (size_t)(n_blk + r) * C_ + gc * 8, &AB[0][1][id * 8]);
    }
    __syncthreads();

    f32x4 acc[4][4] = {};
    for (int tt = 0; tt < 8; tt++) {
        const __hip_bfloat16* As = AB[tt & 1][0];
        const __hip_bfloat16* Bs = AB[tt & 1][1];
        if (tt < 7) {
            int kk = (tt + 1) * 64;
            __hip_bfloat16* An = AB[(tt + 1) & 1][0];
            __hip_bfloat16* Bn = AB[(tt + 1) & 1][1];
#pragma unroll
            for (int i = 0; i < 4; i++) {
                int id = i * 256 + t;
                int r = id >> 3, cx = id & 7, gc = cx ^ (r & 7);
                load_lds16(Wbf + (size_t)(m_blk + r) * C_ + kk + gc * 8, &An[id * 8]);
                load_lds16(xTb + (size_t)(n_blk + r) * C_ + kk + gc * 8, &Bn[id * 8]);
            }
        }
#pragma unroll
        for (int h = 0; h < 2; h++) {
            bf16x8 af[4], bfr[4];
#pragma unroll
            for (int i = 0; i < 4; i++) {
                int ra = wm * 64 + i * 16 + lr;
                int rb = wn * 64 + i * 16 + lr;
                int q = h * 4 + quad;
                af[i]  = *(const bf16x8*)&As[ra * 64 + (q ^ (lr & 7)) * 8];
                bfr[i] = *(const bf16x8*)&Bs[rb * 64 + (q ^ (lr & 7)) * 8];
            }
#pragma unroll
            for (int mt = 0; mt < 4; mt++)
#pragma unroll
                for (int nt = 0; nt < 4; nt++)
                    acc[mt][nt] = MFMA16(af[mt], bfr[nt], acc[mt][nt]);
        }
        __syncthreads();   // drains next-tile stage (vmcnt) + read fences
    }

    // epilogue (epi lives in AB[0], dead after last tile which read AB[1];
    // epi slices are wave-private so no extra barrier needed)
#pragma unroll
    for (int mt = 0; mt < 4; mt++) {
        int m_frag = m_blk + wm * 64 + mt * 16;
        if (m_frag >= D_ + C_) continue;
        int m0 = m_frag + quad * 4;
        if (m_frag < D_) {
#pragma unroll
            for (int nt = 0; nt < 4; nt++) {
                int n = n_blk + wn * 64 + nt * 16 + lr;
                alignas(8) __hip_bfloat16 tmp[4];
#pragma unroll
                for (int r = 0; r < 4; r++)
                    tmp[r] = __float2bfloat16(acc[mt][nt][r] + b1[m0 + r]);
                *reinterpret_cast<short4*>(qkT + ((size_t)b * N_ + n) * D_ + m0) =
                    *reinterpret_cast<short4*>(tmp);
            }
        } else {
#pragma unroll
            for (int nt = 0; nt < 4; nt++) {
#pragma unroll
                for (int r = 0; r < 4; r++) {
                    int c = m0 - D_ + r;
                    epi[(wave * 16 + quad * 4 + r) * 72 + nt * 16 + lr] =
                        __float2bfloat16(acc[mt][nt][r] + b2[c]);
                }
            }
            int cbase = m_frag - D_;
            int row = lane >> 2;
#pragma unroll
            for (int it = 0; it < 2; it++) {
                int col = it * 32 + (lane & 3) * 8;
                bf16x8 frag = *(const bf16x8*)&epi[(wave * 16 + row) * 72 + col];
                *(bf16x8*)(v + (size_t)(b * C_ + cbase + row) * N_
                             + n_blk + wn * 64 + col) = frag;
            }
        }
    }
}

// ---------------------------------------------------------------------------
// K3: fused flash attention + PV GEMM + residual, full c-width per block.
// Grid (b=32, n=8) -> XCD = b%8 (v[b], qkT[b] L2-resident). ROUND-3 proven
// structure restored: Vs double-buffered in LDS (coalesced global_load_lds,
// stage issued at tile start, in flight across the lgkm-only mid barrier,
// drained at end-of-tile __syncthreads); Ks single-buffered, staged during
// PV. Round-6 additions: (a) s_setprio(1) around the PV MFMA cluster (T5 —
// waves are phase-split here, scheduler can favor MFMA-entering waves);
// (b) softmax shift folded into MFMA C-input (s starts at -shift; C/D col
// = lane's n, shift is per-n, so all 4 regs share the lane's shift).
// LDS: Ks 8K + Vs0 64K + Vs1 64K + Ps 16K = 152 KB (1 block/CU; grid=256).
// Register budget: acc[4][8]=128 AGPR + ~124 VGPR — NO new persistent
// register state (round-4 lesson: reg-K spilled at 64 extra VGPRs).
// ---------------------------------------------------------------------------
__global__ __launch_bounds__(512, 2) void k_fused_attn(
        const __hip_bfloat16* __restrict__ qkT,
        const __hip_bfloat16* __restrict__ v,
        const float* __restrict__ x, float* __restrict__ out) {
    __shared__ char smem[155648];
    __hip_bfloat16* Ks  = (__hip_bfloat16*)smem;             // [64][64]    8 KB
    __hip_bfloat16* Vs0 = (__hip_bfloat16*)(smem + 8192);    // [512][64]  64 KB
    __hip_bfloat16* Vs1 = (__hip_bfloat16*)(smem + 73728);   // [512][64]  64 KB
    __hip_bfloat16* Ps  = (__hip_bfloat16*)(smem + 139264);  // [128][64]  16 KB
    float* Obuf = (float*)smem;                              // [64][260] fp32 epi
    float* Rs   = (float*)(smem + 66560);                    // [128] rowinv (dead Vs0)

    int b = blockIdx.x;
    int t = threadIdx.x;
    int wave = t >> 6, lane = t & 63, lr = lane & 15, quad = lane >> 4;
    int wm = wave >> 2, wn = wave & 3;
    int n_blk = blockIdx.y * 128;
    const __hip_bfloat16* qb = qkT + (size_t)b * (N_ * D_);
    const __hip_bfloat16* vb = v + (size_t)b * (C_ * N_);

    // prologue: stage tile 0 (Ks + Vs0); Q-fragment loads overlap the latency
    {
        int r = t >> 3, cxx = t & 7, gc = cxx ^ (r & 7);
        load_lds16(qb + (size_t)r * D_ + gc * 8, &Ks[t * 8]);
    }
#pragma unroll
    for (int i = 0; i < 8; i++) {
        int id = i * 512 + t;
        int r = id >> 3, cxx = id & 7, gc = cxx ^ (r & 7);
        load_lds16(vb + (size_t)r * N_ + gc * 8, &Vs0[id * 8]);
    }

    // Q fragment (B operand of S^T) + softmax shift = ||q_n||^2 (diagonal):
    // rowsum >= 1 (diag term e^0), off-diag exp <= ~e^30 -> fp32/bf16 safe.
    union bfu { bf16x8 v; __hip_bfloat16 h[8]; };
    bf16x8 bq[2];
    float nshift;
    {
        int nq = n_blk + wave * 16 + lr;
        bq[0] = *(const bf16x8*)(qb + (size_t)nq * D_ + quad * 8);
        bq[1] = *(const bf16x8*)(qb + (size_t)nq * D_ + 32 + quad * 8);
        float sq = 0.f;
#pragma unroll
        for (int dh = 0; dh < 2; dh++) {
            bfu u; u.v = bq[dh];
#pragma unroll
            for (int j = 0; j < 8; j++) {
                float qv = __bfloat162float(u.h[j]);
                sq += qv * qv;
            }
        }
        sq += __shfl_xor(sq, 16);
        sq += __shfl_xor(sq, 32);   // full ||q_n||^2 across the 4 quads
        nshift = -sq;               // folded into MFMA C-input
    }

    f32x4 acc[4][8] = {};
    float rsum = 0.f;

    __syncthreads();   // vmcnt(0) drain: tile 0 staged

    for (int tt = 0; tt < 16; ++tt) {
        int kk = tt * 64;
        __hip_bfloat16* Vcur = (tt & 1) ? Vs1 : Vs0;
        __hip_bfloat16* Vnxt = (tt & 1) ? Vs0 : Vs1;

        // issue Vs stage for t+1 (completes under this tile's compute)
        if (tt < 15) {
#pragma unroll
            for (int i = 0; i < 8; i++) {
                int id = i * 512 + t;
                int r = id >> 3, cxx = id & 7, gc = cxx ^ (r & 7);
                load_lds16(vb + (size_t)r * N_ + kk + 64 + gc * 8, &Vnxt[id * 8]);
            }
        }

        // S-phase: this wave's 16 n-cols x 64 m; exp + rowsum + Ps write.
        // MFMA C-input starts at -shift: s = q.k - ||q_n||^2 directly.
#pragma unroll
        for (int mi = 0; mi < 4; mi++) {
            int m = mi * 16 + lr;
            bf16x8 ak0 = *(const bf16x8*)&Ks[m * 64 + ((quad) ^ (lr & 7)) * 8];
            bf16x8 ak1 = *(const bf16x8*)&Ks[m * 64 + ((4 + quad) ^ (lr & 7)) * 8];
            f32x4 s = {nshift, nshift, nshift, nshift};
            s = MFMA16(ak0, bq[0], s);
            s = MFMA16(ak1, bq[1], s);
            alignas(8) __hip_bfloat16 tmp[4];
#pragma unroll
            for (int r = 0; r < 4; r++) {
                float e = __expf(s[r]);
                rsum += e;
                tmp[r] = __float2bfloat16(e);
            }
            // lane holds m = mi*16 + quad*4 + {0..3} (contiguous), col n
            int n = wave * 16 + lr;
            int cx2 = mi * 2 + (quad >> 1);
            int slot = cx2 ^ (lr & 7);
            *(short4*)&Ps[n * 64 + slot * 8 + (quad & 1) * 4] = *(short4*)tmp;
        }

        // mid barrier: LDS ops only — Vs stage stays in flight (vmcnt untouched)
        asm volatile("s_waitcnt lgkmcnt(0)" ::: "memory");
        __builtin_amdgcn_s_barrier();
        __builtin_amdgcn_sched_barrier(0);

        // stage next Ks during PV (Ks reads finished before mid barrier)
        if (tt < 15) {
            int r = t >> 3, cxx = t & 7, gc = cxx ^ (r & 7);
            load_lds16(qb + (size_t)(kk + 64 + r) * D_ + gc * 8, &Ks[t * 8]);
        }

        // PV: acc[n 64][c 128] += Ps (A) x Vcur (B); setprio keeps the
        // matrix pipe fed while other waves issue staging VMEM.
        __builtin_amdgcn_s_setprio(1);
#pragma unroll
        for (int h = 0; h < 2; h++) {
            bf16x8 af[4];
#pragma unroll
            for (int i = 0; i < 4; i++) {
                int ra = wm * 64 + i * 16 + lr;
                af[i] = *(const bf16x8*)&Ps[ra * 64 + ((h * 4 + quad) ^ (lr & 7)) * 8];
            }
#pragma unroll
            for (int g = 0; g < 2; g++) {
                bf16x8 bfr[4];
#pragma unroll
                for (int j = 0; j < 4; j++) {
                    int rb = wn * 128 + (g * 4 + j) * 16 + lr;
                    bfr[j] = *(const bf16x8*)&Vcur[rb * 64 + ((h * 4 + quad) ^ (lr & 7)) * 8];
                }
#pragma unroll
                for (int mt = 0; mt < 4; mt++)
#pragma unroll
                    for (int j = 0; j < 4; j++)
                        acc[mt][g * 4 + j] = MFMA16(af[mt], bfr[j], acc[mt][g * 4 + j]);
            }
        }
        __builtin_amdgcn_s_setprio(0);
        __syncthreads();   // vmcnt(0)+lgkmcnt(0): next tile's Vs/Ks landed
    }

    // rowinv: reduce partial sums across the 4 quads (Rs in dead Vs0 region)
    rsum += __shfl_xor(rsum, 16);
    rsum += __shfl_xor(rsum, 32);
    if (quad == 0) Rs[wave * 16 + lr] = 1.0f / rsum;

    // epilogue: 4 phases (h = n-half, g = c-half) through LDS Obuf[64][260]
    const float* xb = x + (size_t)b * (N_ * C_);
    float* ob = out + (size_t)b * (N_ * C_);
#pragma unroll
    for (int h = 0; h < 2; h++) {
#pragma unroll
        for (int g = 0; g < 2; g++) {
            __syncthreads();   // Obuf free; also publishes Rs on first pass
            if (wm == h && (wn >> 1) == g) {
#pragma unroll
                for (int mt = 0; mt < 4; mt++)
#pragma unroll
                    for (int nt = 0; nt < 8; nt++)
#pragma unroll
                        for (int r = 0; r < 4; r++)
                            Obuf[(mt * 16 + quad * 4 + r) * 260
                                 + (wn & 1) * 128 + nt * 16 + lr] =
                                acc[mt][nt][r];
            }
            __syncthreads();
#pragma unroll
            for (int i = 0; i < 8; i++) {
                int id = i * 512 + t;
                int rl = id >> 6;              // 0..63 (= i*8 + wave)
                int c4 = (id & 63) * 4;        // float4 col 0..252
                int n = n_blk + h * 64 + rl;
                float ri = Rs[h * 64 + rl];
                float4v o = *(const float4v*)&Obuf[rl * 260 + c4];
                size_t gidx = (size_t)n * C_ + g * 256 + c4;
                float4v xv = *(const float4v*)(xb + gidx);
                float4v res;
                res.x = xv.x + ri * o.x;
                res.y = xv.y + ri * o.y;
                res.z = xv.z + ri * o.z;
                res.w = xv.w + ri * o.w;
                *(float4v*)(ob + gidx) = res;
            }
        }
    }
}

// ---------------------------------------------------------------------------
extern "C" void kernel_launch(void* const* d_in, const int* in_sizes, int n_in,
                              void* d_out, int out_size, void* d_ws, size_t ws_size,
                              hipStream_t stream) {
    const float* x  = (const float*)d_in[0];
    const float* w1 = (const float*)d_in[1];
    const float* b1 = (const float*)d_in[2];
    const float* w2 = (const float*)d_in[3];
    const float* b2 = (const float*)d_in[4];
    float* out = (float*)d_out;

    char* ws = (char*)d_ws;
    size_t off = 0;
    __hip_bfloat16* Wbf = (__hip_bfloat16*)(ws + off); off += (size_t)OPAD * C_ * 2;
    __hip_bfloat16* xT  = (__hip_bfloat16*)(ws + off); off += (size_t)B_ * N_ * C_ * 2;
    __hip_bfloat16* qkT = (__hip_bfloat16*)(ws + off); off += (size_t)B_ * N_ * D_ * 2;
    __hip_bfloat16* v   = (__hip_bfloat16*)(ws + off); off += (size_t)B_ * C_ * N_ * 2;

    hipLaunchKernelGGL(k_transpose_cast, dim3(N_ / 64, C_ / 64, B_), dim3(256), 0, stream,
                       x, w1, w2, xT, Wbf);
    hipLaunchKernelGGL(k_gemm_qkv, dim3(B_, N_ / 128, OPAD / 128), dim3(256), 0, stream,
                       Wbf, xT, b1, b2, qkT, v);
    hipLaunchKernelGGL(k_fused_attn, dim3(B_, N_ / 128), dim3(512), 0, stream,
                       qkT, v, x, out);
}